// Round 9
// baseline (737.852 us; speedup 1.0000x reference)
//
#include <hip/hip_runtime.h>
#include <hip/hip_fp16.h>

#define N_NODES 65536
#define N_EDGES 1048576
#define D_FEAT  64
#define BUCKET  64   // padded CSR bucket slots per node (deg ~ Poisson(16); max deg << 64)
#define DEGBINS 64

typedef float vfloat4 __attribute__((ext_vector_type(4)));

// ---------------- workspace layout (bytes) ----------------
// counts : N int        @ 0x000000   (256 KB)
// dinv   : N float      @ 0x040000   (256 KB)
// rank   : E int        @ 0x080000   (4 MB)
// perm   : N int        @ 0x480000   (256 KB)  nodes sorted by degree
// hist   : 64 int       @ 0x4C0000
// cur    : 64 int       @ 0x4C0400
// csr_src: N*64 int     @ 0x500000   (16 MB, zeroed; holes gather row 0, masked)
// tA     : N*64 half    @ 0x1500000  (8 MB)   t = dinv .* p  (Horner state, fp16)
// tB     : N*64 half    @ 0x1D00000  (8 MB)

__global__ void count_deg(const int* __restrict__ dst, int* __restrict__ counts,
                          int* __restrict__ rank) {
    int e = blockIdx.x * blockDim.x + threadIdx.x;
    if (e < N_EDGES) rank[e] = atomicAdd(&counts[dst[e]], 1);
}

__global__ void compute_dinv(const int* __restrict__ counts, float* __restrict__ dinv) {
    int v = blockIdx.x * blockDim.x + threadIdx.x;
    if (v < N_NODES) dinv[v] = rsqrtf((float)(counts[v] + 1));  // +1 self-loop
}

// degree histogram (64 bins)
__global__ void hist_deg(const int* __restrict__ counts, int* __restrict__ hist) {
    int v = blockIdx.x * blockDim.x + threadIdx.x;
    int d = min(counts[v], DEGBINS - 1);
    atomicAdd(&hist[d], 1);
}

// exclusive scan of the 64-bin histogram; one block of 64 threads
__global__ void scan_hist(const int* __restrict__ hist, int* __restrict__ cur) {
    __shared__ int s[DEGBINS];
    int t = threadIdx.x;
    int v = hist[t];
    s[t] = v;
    __syncthreads();
    for (int o = 1; o < DEGBINS; o <<= 1) {
        int u = (t >= o) ? s[t - o] : 0;
        __syncthreads();
        s[t] += u;
        __syncthreads();
    }
    cur[t] = s[t] - v;  // exclusive
}

// counting-sort scatter: perm = node ids ordered by degree
__global__ void make_perm(const int* __restrict__ counts, int* __restrict__ cur,
                          int* __restrict__ perm) {
    int v = blockIdx.x * blockDim.x + threadIdx.x;
    int d = min(counts[v], DEGBINS - 1);
    int pos = atomicAdd(&cur[d], 1);
    perm[pos] = v;
}

// pos = d*BUCKET + rank[e]; only src stored (weights folded into the table)
__global__ void scatter_src(const int* __restrict__ src, const int* __restrict__ dst,
                            const int* __restrict__ rank, int* __restrict__ csr_src) {
    int e = blockIdx.x * blockDim.x + threadIdx.x;
    if (e >= N_EDGES) return;
    csr_src[dst[e] * BUCKET + rank[e]] = src[e];
}

// t0[v] = fp16(dinv[v] * x[v])  (invariant: table t_k = dinv .* p_k)
__global__ void cvt_x(const float* __restrict__ x, const float* __restrict__ dinv,
                      __half* __restrict__ t0) {
    int i = blockIdx.x * blockDim.x + threadIdx.x;  // i < N*16
    int v = i >> 4;
    float dv = dinv[v];
    float4 val = ((const float4*)x)[i];
    __half2 lo = __floats2half2_rn(dv * val.x, dv * val.y);
    __half2 hi = __floats2half2_rn(dv * val.z, dv * val.w);
    unsigned long long o = ((unsigned long long)(*(const unsigned int*)&hi) << 32)
                         | (*(const unsigned int*)&lo);
    ((unsigned long long*)t0)[i] = o;
}

// Horner hop, dinv folded:  p_out[d] = sc*dinv[d]*(sum_e t[src_e] + t[d]) + temp[k]*x[d]
//                           t_out[d] = dinv[d]*p_out[d]  (k<9; k==9 writes p fp32)
// FOUR degree-sorted nodes per wave (perm[4w..4w+3], near-equal degree -> minimal
// masked-slot waste). lane = 16q+f: q = edge slot 0..3, f = feature quad (8 B;
// 16 lanes = 128 B row). Granule = 4 edges/node/step, unroll 4 -> up to 16
// independent gathers in flight. Holes gather row 0 (L1-hot), masked off.
__global__ void __launch_bounds__(256) hop_kernel(
        const __half* __restrict__ tab, const float* __restrict__ x,
        __half* __restrict__ tab_out, float* __restrict__ out_f32,
        const float* __restrict__ temp, const int* __restrict__ counts,
        const int* __restrict__ csr_src, const float* __restrict__ dinv,
        const int* __restrict__ perm, int k) {
    int gtid = blockIdx.x * blockDim.x + threadIdx.x;
    int wave = __builtin_amdgcn_readfirstlane(gtid >> 6);
    int lane = gtid & 63;
    int q = lane >> 4;   // edge slot within granule of 4
    int f = lane & 15;   // feature quad

    float tk = temp[k];
    float sc = (k == 1) ? temp[0] : 1.0f;

    int4 pv = *(const int4*)(perm + wave * 4);   // wave-uniform -> s_load_dwordx4
    int vids[4] = {pv.x, pv.y, pv.z, pv.w};
    int   cnt[4];
    float dv[4];
    #pragma unroll
    for (int j = 0; j < 4; ++j) {
        cnt[j] = counts[vids[j]];
        dv[j]  = dinv[vids[j]];
    }
    int maxc = max(max(cnt[0], cnt[1]), max(cnt[2], cnt[3]));  // ~= all cnts (sorted)
    int iters = (maxc + 3) >> 2;   // 4 edges per node per step

    const unsigned long long* t2 = (const unsigned long long*)tab;  // 8 B granule
    float a0[4] = {0.f, 0.f, 0.f, 0.f};
    float a1[4] = {0.f, 0.f, 0.f, 0.f};
    float a2[4] = {0.f, 0.f, 0.f, 0.f};
    float a3[4] = {0.f, 0.f, 0.f, 0.f};

    #pragma unroll 4
    for (int r = 0; r < iters; ++r) {
        int e0 = r * 4;
        #pragma unroll
        for (int j = 0; j < 4; ++j) {
            int4 sg = *(const int4*)(csr_src + vids[j] * BUCKET + e0);  // scalar
            int s01 = (q & 1) ? sg.y : sg.x;
            int s23 = (q & 1) ? sg.w : sg.z;
            int s   = (q & 2) ? s23 : s01;        // slot (e0+q)'s source node
            bool ok = (e0 + q) < cnt[j];
            unsigned long long row = t2[s * 16 + f];
            unsigned int rl = (unsigned int)row, rh = (unsigned int)(row >> 32);
            float2 lo = __half22float2(*(const __half2*)&rl);
            float2 hi = __half22float2(*(const __half2*)&rh);
            a0[j] += ok ? lo.x : 0.0f;
            a1[j] += ok ? lo.y : 0.0f;
            a2[j] += ok ? hi.x : 0.0f;
            a3[j] += ok ? hi.y : 0.0f;
        }
    }

    #pragma unroll
    for (int j = 0; j < 4; ++j) {
        a0[j] += __shfl_xor(a0[j], 16); a0[j] += __shfl_xor(a0[j], 32);
        a1[j] += __shfl_xor(a1[j], 16); a1[j] += __shfl_xor(a1[j], 32);
        a2[j] += __shfl_xor(a2[j], 16); a2[j] += __shfl_xor(a2[j], 32);
        a3[j] += __shfl_xor(a3[j], 16); a3[j] += __shfl_xor(a3[j], 32);
    }

    #pragma unroll
    for (int j = 0; j < 4; ++j) {
        int v = vids[j];
        vfloat4 xv = ((const vfloat4*)x)[v * 16 + f];
        unsigned long long srow = t2[v * 16 + f];   // self term t[d]
        unsigned int sl = (unsigned int)srow, sh = (unsigned int)(srow >> 32);
        float2 slo = __half22float2(*(const __half2*)&sl);
        float2 shi = __half22float2(*(const __half2*)&sh);
        float m = sc * dv[j];
        float r0 = m * (a0[j] + slo.x) + tk * xv.x;
        float r1 = m * (a1[j] + slo.y) + tk * xv.y;
        float r2 = m * (a2[j] + shi.x) + tk * xv.z;
        float r3 = m * (a3[j] + shi.y) + tk * xv.w;
        if (q == 0) {
            if (k == 9) {
                vfloat4 o = {r0, r1, r2, r3};
                ((vfloat4*)out_f32)[v * 16 + f] = o;
            } else {
                float d2 = dv[j];
                __half2 lo = __floats2half2_rn(d2 * r0, d2 * r1);
                __half2 hi = __floats2half2_rn(d2 * r2, d2 * r3);
                unsigned long long o =
                    ((unsigned long long)(*(const unsigned int*)&hi) << 32)
                    | (*(const unsigned int*)&lo);
                ((unsigned long long*)tab_out)[v * 16 + f] = o;
            }
        }
    }
}

extern "C" void kernel_launch(void* const* d_in, const int* in_sizes, int n_in,
                              void* d_out, int out_size, void* d_ws, size_t ws_size,
                              hipStream_t stream) {
    const float* x    = (const float*)d_in[0];
    const float* temp = (const float*)d_in[1];
    const int*   ei   = (const int*)d_in[2];
    const int* src = ei;             // edge_index[0]
    const int* dst = ei + N_EDGES;   // edge_index[1]
    float* out = (float*)d_out;

    char* ws = (char*)d_ws;
    int*    counts  = (int*)   (ws + 0x000000);
    float*  dinv    = (float*) (ws + 0x040000);
    int*    rank    = (int*)   (ws + 0x080000);
    int*    perm    = (int*)   (ws + 0x480000);
    int*    hist    = (int*)   (ws + 0x4C0000);
    int*    cur     = (int*)   (ws + 0x4C0400);
    int*    csr_src = (int*)   (ws + 0x500000);   // 16 MB
    __half* tA      = (__half*)(ws + 0x1500000);
    __half* tB      = (__half*)(ws + 0x1D00000);

    (void)hipMemsetAsync(counts, 0, N_NODES * sizeof(int), stream);
    (void)hipMemsetAsync(hist, 0, DEGBINS * sizeof(int), stream);
    (void)hipMemsetAsync(csr_src, 0, N_NODES * BUCKET * sizeof(int), stream);

    count_deg<<<N_EDGES / 256, 256, 0, stream>>>(dst, counts, rank);
    compute_dinv<<<N_NODES / 256, 256, 0, stream>>>(counts, dinv);
    hist_deg<<<N_NODES / 256, 256, 0, stream>>>(counts, hist);
    scan_hist<<<1, DEGBINS, 0, stream>>>(hist, cur);
    make_perm<<<N_NODES / 256, 256, 0, stream>>>(counts, cur, perm);
    scatter_src<<<N_EDGES / 256, 256, 0, stream>>>(src, dst, rank, csr_src);
    cvt_x<<<(N_NODES * 16) / 256, 256, 0, stream>>>(x, dinv, tA);

    // Horner: p = temp[0]*x; for k=1..9: p = A_hat*p + temp[k]*x (scale fused in hop1)
    // Table invariant t_k = dinv .* p_k; chain tA -> tB -> tA -> ...
    const int hop_blocks = (N_NODES / 4) * 64 / 256;  // 4 nodes per wave
    const __half* gin = tA;
    for (int k = 1; k <= 9; ++k) {
        __half* gout = (k & 1) ? tB : tA;
        hop_kernel<<<hop_blocks, 256, 0, stream>>>(gin, x, gout, out, temp,
                                                   counts, csr_src, dinv, perm, k);
        gin = gout;
    }
}

// Round 10
// 399.075 us; speedup vs baseline: 1.8489x; 1.8489x over previous
//
#include <hip/hip_runtime.h>
#include <hip/hip_fp16.h>

#define N_NODES 65536
#define N_EDGES 1048576
#define D_FEAT  64
#define BUCKET  64   // padded CSR bucket slots per node (deg ~ Poisson(16); max deg << 64)
#define DEGBINS 64

typedef float vfloat4 __attribute__((ext_vector_type(4)));

// ---------------- workspace layout (bytes) ----------------
// counts : N int        @ 0x000000   (256 KB)
// dinv   : N float      @ 0x040000   (256 KB)
// rank   : E int        @ 0x080000   (4 MB)
// perm   : N int        @ 0x480000   (256 KB)  nodes sorted by degree
// hist   : 64 int       @ 0x4C0000
// cur    : 64 int       @ 0x4C0400
// csr_src: N*64 int     @ 0x500000   (16 MB, zeroed; holes gather row 0, masked)
// tA     : N*64 half    @ 0x1500000  (8 MB)   t = dinv .* p  (Horner state, fp16)
// tB     : N*64 half    @ 0x1D00000  (8 MB)

__global__ void count_deg(const int* __restrict__ dst, int* __restrict__ counts,
                          int* __restrict__ rank) {
    int e = blockIdx.x * blockDim.x + threadIdx.x;
    if (e < N_EDGES) rank[e] = atomicAdd(&counts[dst[e]], 1);
}

__global__ void compute_dinv(const int* __restrict__ counts, float* __restrict__ dinv) {
    int v = blockIdx.x * blockDim.x + threadIdx.x;
    if (v < N_NODES) dinv[v] = rsqrtf((float)(counts[v] + 1));  // +1 self-loop
}

// degree histogram: LDS-aggregated per block, then 64 spread global atomics/block
__global__ void hist_deg(const int* __restrict__ counts, int* __restrict__ hist) {
    __shared__ int lh[DEGBINS];
    int tid = threadIdx.x;
    if (tid < DEGBINS) lh[tid] = 0;
    __syncthreads();
    int v = blockIdx.x * blockDim.x + tid;
    int d = min(counts[v], DEGBINS - 1);
    atomicAdd(&lh[d], 1);
    __syncthreads();
    if (tid < DEGBINS && lh[tid] > 0) atomicAdd(&hist[tid], lh[tid]);
}

// exclusive scan of the 64-bin histogram; one block of 64 threads
__global__ void scan_hist(const int* __restrict__ hist, int* __restrict__ cur) {
    __shared__ int s[DEGBINS];
    int t = threadIdx.x;
    int v = hist[t];
    s[t] = v;
    __syncthreads();
    for (int o = 1; o < DEGBINS; o <<= 1) {
        int u = (t >= o) ? s[t - o] : 0;
        __syncthreads();
        s[t] += u;
        __syncthreads();
    }
    cur[t] = s[t] - v;  // exclusive
}

// counting-sort scatter with LDS aggregation: local rank via LDS atomic, one
// global atomicAdd per (block,bin) to reserve the base. Order within a bin is
// nondeterministic, but any in-bin order is a valid node->wave assignment.
__global__ void make_perm(const int* __restrict__ counts, int* __restrict__ cur,
                          int* __restrict__ perm) {
    __shared__ int lh[DEGBINS];
    __shared__ int base[DEGBINS];
    int tid = threadIdx.x;
    if (tid < DEGBINS) lh[tid] = 0;
    __syncthreads();
    int v = blockIdx.x * blockDim.x + tid;
    int d = min(counts[v], DEGBINS - 1);
    int lr = atomicAdd(&lh[d], 1);
    __syncthreads();
    if (tid < DEGBINS) base[tid] = (lh[tid] > 0) ? atomicAdd(&cur[tid], lh[tid]) : 0;
    __syncthreads();
    perm[base[d] + lr] = v;
}

// pos = d*BUCKET + rank[e]; only src stored (weights folded into the table)
__global__ void scatter_src(const int* __restrict__ src, const int* __restrict__ dst,
                            const int* __restrict__ rank, int* __restrict__ csr_src) {
    int e = blockIdx.x * blockDim.x + threadIdx.x;
    if (e >= N_EDGES) return;
    csr_src[dst[e] * BUCKET + rank[e]] = src[e];
}

// t0[v] = fp16(dinv[v] * x[v])  (invariant: table t_k = dinv .* p_k)
__global__ void cvt_x(const float* __restrict__ x, const float* __restrict__ dinv,
                      __half* __restrict__ t0) {
    int i = blockIdx.x * blockDim.x + threadIdx.x;  // i < N*16
    int v = i >> 4;
    float dv = dinv[v];
    float4 val = ((const float4*)x)[i];
    __half2 lo = __floats2half2_rn(dv * val.x, dv * val.y);
    __half2 hi = __floats2half2_rn(dv * val.z, dv * val.w);
    unsigned long long o = ((unsigned long long)(*(const unsigned int*)&hi) << 32)
                         | (*(const unsigned int*)&lo);
    ((unsigned long long*)t0)[i] = o;
}

// Horner hop, dinv folded:  p_out[d] = sc*dinv[d]*(sum_e t[src_e] + t[d]) + temp[k]*x[d]
//                           t_out[d] = dinv[d]*p_out[d]  (k<9; k==9 writes p fp32)
// FOUR degree-sorted nodes per wave (perm[4w..4w+3], near-equal degree -> minimal
// masked-slot waste). lane = 16q+f: q = edge slot 0..3, f = feature quad (8 B;
// 16 lanes = 128 B row). Granule = 4 edges/node/step, unroll 4 -> up to 16
// independent gathers in flight. Holes gather row 0 (L1-hot), masked off.
__global__ void __launch_bounds__(256) hop_kernel(
        const __half* __restrict__ tab, const float* __restrict__ x,
        __half* __restrict__ tab_out, float* __restrict__ out_f32,
        const float* __restrict__ temp, const int* __restrict__ counts,
        const int* __restrict__ csr_src, const float* __restrict__ dinv,
        const int* __restrict__ perm, int k) {
    int gtid = blockIdx.x * blockDim.x + threadIdx.x;
    int wave = __builtin_amdgcn_readfirstlane(gtid >> 6);
    int lane = gtid & 63;
    int q = lane >> 4;   // edge slot within granule of 4
    int f = lane & 15;   // feature quad

    float tk = temp[k];
    float sc = (k == 1) ? temp[0] : 1.0f;

    int4 pv = *(const int4*)(perm + wave * 4);   // wave-uniform -> s_load_dwordx4
    int vids[4] = {pv.x, pv.y, pv.z, pv.w};
    int   cnt[4];
    float dv[4];
    #pragma unroll
    for (int j = 0; j < 4; ++j) {
        cnt[j] = counts[vids[j]];
        dv[j]  = dinv[vids[j]];
    }
    int maxc = max(max(cnt[0], cnt[1]), max(cnt[2], cnt[3]));  // ~= all cnts (sorted)
    int iters = (maxc + 3) >> 2;   // 4 edges per node per step

    const unsigned long long* t2 = (const unsigned long long*)tab;  // 8 B granule
    float a0[4] = {0.f, 0.f, 0.f, 0.f};
    float a1[4] = {0.f, 0.f, 0.f, 0.f};
    float a2[4] = {0.f, 0.f, 0.f, 0.f};
    float a3[4] = {0.f, 0.f, 0.f, 0.f};

    #pragma unroll 4
    for (int r = 0; r < iters; ++r) {
        int e0 = r * 4;
        #pragma unroll
        for (int j = 0; j < 4; ++j) {
            int4 sg = *(const int4*)(csr_src + vids[j] * BUCKET + e0);  // scalar
            int s01 = (q & 1) ? sg.y : sg.x;
            int s23 = (q & 1) ? sg.w : sg.z;
            int s   = (q & 2) ? s23 : s01;        // slot (e0+q)'s source node
            bool ok = (e0 + q) < cnt[j];
            unsigned long long row = t2[s * 16 + f];
            unsigned int rl = (unsigned int)row, rh = (unsigned int)(row >> 32);
            float2 lo = __half22float2(*(const __half2*)&rl);
            float2 hi = __half22float2(*(const __half2*)&rh);
            a0[j] += ok ? lo.x : 0.0f;
            a1[j] += ok ? lo.y : 0.0f;
            a2[j] += ok ? hi.x : 0.0f;
            a3[j] += ok ? hi.y : 0.0f;
        }
    }

    #pragma unroll
    for (int j = 0; j < 4; ++j) {
        a0[j] += __shfl_xor(a0[j], 16); a0[j] += __shfl_xor(a0[j], 32);
        a1[j] += __shfl_xor(a1[j], 16); a1[j] += __shfl_xor(a1[j], 32);
        a2[j] += __shfl_xor(a2[j], 16); a2[j] += __shfl_xor(a2[j], 32);
        a3[j] += __shfl_xor(a3[j], 16); a3[j] += __shfl_xor(a3[j], 32);
    }

    #pragma unroll
    for (int j = 0; j < 4; ++j) {
        int v = vids[j];
        vfloat4 xv = ((const vfloat4*)x)[v * 16 + f];
        unsigned long long srow = t2[v * 16 + f];   // self term t[d]
        unsigned int sl = (unsigned int)srow, sh = (unsigned int)(srow >> 32);
        float2 slo = __half22float2(*(const __half2*)&sl);
        float2 shi = __half22float2(*(const __half2*)&sh);
        float m = sc * dv[j];
        float r0 = m * (a0[j] + slo.x) + tk * xv.x;
        float r1 = m * (a1[j] + slo.y) + tk * xv.y;
        float r2 = m * (a2[j] + shi.x) + tk * xv.z;
        float r3 = m * (a3[j] + shi.y) + tk * xv.w;
        if (q == 0) {
            if (k == 9) {
                vfloat4 o = {r0, r1, r2, r3};
                ((vfloat4*)out_f32)[v * 16 + f] = o;
            } else {
                float d2 = dv[j];
                __half2 lo = __floats2half2_rn(d2 * r0, d2 * r1);
                __half2 hi = __floats2half2_rn(d2 * r2, d2 * r3);
                unsigned long long o =
                    ((unsigned long long)(*(const unsigned int*)&hi) << 32)
                    | (*(const unsigned int*)&lo);
                ((unsigned long long*)tab_out)[v * 16 + f] = o;
            }
        }
    }
}

extern "C" void kernel_launch(void* const* d_in, const int* in_sizes, int n_in,
                              void* d_out, int out_size, void* d_ws, size_t ws_size,
                              hipStream_t stream) {
    const float* x    = (const float*)d_in[0];
    const float* temp = (const float*)d_in[1];
    const int*   ei   = (const int*)d_in[2];
    const int* src = ei;             // edge_index[0]
    const int* dst = ei + N_EDGES;   // edge_index[1]
    float* out = (float*)d_out;

    char* ws = (char*)d_ws;
    int*    counts  = (int*)   (ws + 0x000000);
    float*  dinv    = (float*) (ws + 0x040000);
    int*    rank    = (int*)   (ws + 0x080000);
    int*    perm    = (int*)   (ws + 0x480000);
    int*    hist    = (int*)   (ws + 0x4C0000);
    int*    cur     = (int*)   (ws + 0x4C0400);
    int*    csr_src = (int*)   (ws + 0x500000);   // 16 MB
    __half* tA      = (__half*)(ws + 0x1500000);
    __half* tB      = (__half*)(ws + 0x1D00000);

    (void)hipMemsetAsync(counts, 0, N_NODES * sizeof(int), stream);
    (void)hipMemsetAsync(hist, 0, DEGBINS * sizeof(int), stream);
    (void)hipMemsetAsync(csr_src, 0, N_NODES * BUCKET * sizeof(int), stream);

    count_deg<<<N_EDGES / 256, 256, 0, stream>>>(dst, counts, rank);
    compute_dinv<<<N_NODES / 256, 256, 0, stream>>>(counts, dinv);
    hist_deg<<<N_NODES / 256, 256, 0, stream>>>(counts, hist);
    scan_hist<<<1, DEGBINS, 0, stream>>>(hist, cur);
    make_perm<<<N_NODES / 256, 256, 0, stream>>>(counts, cur, perm);
    scatter_src<<<N_EDGES / 256, 256, 0, stream>>>(src, dst, rank, csr_src);
    cvt_x<<<(N_NODES * 16) / 256, 256, 0, stream>>>(x, dinv, tA);

    // Horner: p = temp[0]*x; for k=1..9: p = A_hat*p + temp[k]*x (scale fused in hop1)
    // Table invariant t_k = dinv .* p_k; chain tA -> tB -> tA -> ...
    const int hop_blocks = (N_NODES / 4) * 64 / 256;  // 4 nodes per wave
    const __half* gin = tA;
    for (int k = 1; k <= 9; ++k) {
        __half* gout = (k & 1) ? tB : tA;
        hop_kernel<<<hop_blocks, 256, 0, stream>>>(gin, x, gout, out, temp,
                                                   counts, csr_src, dinv, perm, k);
        gin = gout;
    }
}